// Round 1
// baseline (78.796 us; speedup 1.0000x reference)
//
#include <hip/hip_runtime.h>

#define NB 4
#define NGRID 512
#define NTARGET 1024
#define NBASIS 5
#define NCH 8
#define EPS_F 1e-6f
#define LOG2E 1.4426950408889634f

#if defined(__has_builtin)
#if __has_builtin(__builtin_amdgcn_exp2f)
#define EXP2F(x) __builtin_amdgcn_exp2f(x)
#else
#define EXP2F(x) exp2f(x)
#endif
#else
#define EXP2F(x) exp2f(x)
#endif

// Block: 256 threads. tid -> c = tid&7, tt = (tid>>3)&7, gs = tid>>6 (wave-uniform).
// Grid: NB * (NTARGET/8) = 512 blocks. Each thread owns one (b,t,c) output for a
// quarter of the g-range; LDS reduce across the 4 g-splits in the epilogue.
__global__ __launch_bounds__(256) void final_layer_kernel(
    const float* __restrict__ x_grid,   // (NB, NGRID, NCH)
    const float* __restrict__ h_grid,   // (NB, NGRID, NBASIS, NCH)
    const float* __restrict__ target_x, // (NB, NTARGET, NCH)
    const float* __restrict__ sigma,    // (NBASIS, NCH)
    const float* __restrict__ g_w,      // (1, NBASIS)
    const float* __restrict__ g_b,      // (1,)
    float* __restrict__ out)            // (NB, NTARGET, NCH)
{
    const int tid = threadIdx.x;
    const int c   = tid & 7;
    const int tt  = (tid >> 3) & 7;
    const int gs  = tid >> 6;               // 0..3, wave-uniform
    const int b   = blockIdx.x >> 7;        // blockIdx.x / 128
    const int t   = ((blockIdx.x & 127) << 3) + tt;

    // Per-thread exp2 coefficients: exp(-0.5*d^2/s^2) = exp2(d^2 * coef)
    float coef[NBASIS];
#pragma unroll
    for (int k = 0; k < NBASIS; ++k) {
        float s = __expf(sigma[k * NCH + c]) + EPS_F;
        coef[k] = -0.5f * LOG2E / (s * s);
    }

    const float tx = target_x[(b * NTARGET + t) * NCH + c];

    const float* xg = x_grid + (size_t)(b * NGRID) * NCH + c;
    const float* hg = h_grid + (size_t)(b * NGRID) * NBASIS * NCH + c;

    float acc[NBASIS] = {0.f, 0.f, 0.f, 0.f, 0.f};
    const int g0 = gs * (NGRID / 4);

#pragma unroll 4
    for (int gi = 0; gi < NGRID / 4; ++gi) {
        const int g = g0 + gi;
        const float x  = xg[(size_t)g * NCH];
        const float d  = x - tx;
        const float d2 = d * d;
        const float* hp = hg + (size_t)g * NBASIS * NCH;
#pragma unroll
        for (int k = 0; k < NBASIS; ++k) {
            acc[k] += hp[k * NCH] * EXP2F(d2 * coef[k]);
        }
    }

    // Fold g_w (uniform across lanes -> scalar loads)
    float p = 0.f;
#pragma unroll
    for (int k = 0; k < NBASIS; ++k) p += acc[k] * g_w[k];

    __shared__ float partial[256];
    partial[tid] = p;
    __syncthreads();
    if (gs == 0) {
        float r = p + partial[tid + 64] + partial[tid + 128] + partial[tid + 192]
                + g_b[0];
        out[(b * NTARGET + t) * NCH + c] = r;
    }
}

extern "C" void kernel_launch(void* const* d_in, const int* in_sizes, int n_in,
                              void* d_out, int out_size, void* d_ws, size_t ws_size,
                              hipStream_t stream) {
    const float* x_grid   = (const float*)d_in[0];
    const float* h_grid   = (const float*)d_in[1];
    const float* target_x = (const float*)d_in[2];
    const float* sigma    = (const float*)d_in[3];
    const float* g_w      = (const float*)d_in[4];
    const float* g_b      = (const float*)d_in[5];
    float* out = (float*)d_out;

    dim3 grid(NB * (NTARGET / 8));
    dim3 block(256);
    final_layer_kernel<<<grid, block, 0, stream>>>(
        x_grid, h_grid, target_x, sigma, g_w, g_b, out);
}

// Round 2
// 73.939 us; speedup vs baseline: 1.0657x; 1.0657x over previous
//
#include <hip/hip_runtime.h>

#define NB 4
#define NGRID 512
#define NTARGET 1024
#define NBASIS 5
#define NCH 8
#define EPS_F 1e-6f
#define LOG2E 1.4426950408889634f

#if defined(__has_builtin)
#if __has_builtin(__builtin_amdgcn_exp2f)
#define EXP2F(x) __builtin_amdgcn_exp2f(x)
#else
#define EXP2F(x) exp2f(x)
#endif
#else
#define EXP2F(x) exp2f(x)
#endif

// ws layout (floats): [0..39] coef[k][c]  [40] uniform-flag (int)  [64..64+16384) hw[b][g][c]
#define WS_COEF 0
#define WS_FLAG 40
#define WS_HW   64

// ---------------- Kernel A: coef + uniformity flag + hw = sum_k g_w[k]*h[...,k,...] ----
// grid 64 x 256: one hw element per thread. Block 0 also writes coef + flag.
__global__ __launch_bounds__(256) void prep_kernel(
    const float* __restrict__ h_grid,   // (NB, NGRID, NBASIS, NCH)
    const float* __restrict__ sigma,    // (NBASIS, NCH)
    const float* __restrict__ g_w,      // (1, NBASIS)
    float* __restrict__ ws)
{
    const int tid = threadIdx.x;
    const int idx = blockIdx.x * 256 + tid;   // 0..16383 -> (b,g,c)

    // hw[b,g,c] = sum_k g_w[k] * h[b,g,k,c]
    const int c  = idx & 7;
    const int bg = idx >> 3;                  // b*NGRID + g
    const float* hp = h_grid + (size_t)bg * NBASIS * NCH + c;
    float hw = 0.f;
#pragma unroll
    for (int k = 0; k < NBASIS; ++k) hw += g_w[k] * hp[k * NCH];
    ws[WS_HW + idx] = hw;

    if (blockIdx.x == 0) {
        // coef[k][c] = -0.5*log2e / (exp(sigma)+eps)^2  ; flag = all-equal
        if (tid < NBASIS * NCH) {
            float s = __expf(sigma[tid]) + EPS_F;
            ws[WS_COEF + tid] = -0.5f * LOG2E / (s * s);
        }
        __syncthreads();
        if (tid == 0) {
            const unsigned* cu = (const unsigned*)(ws + WS_COEF);
            int eq = 1;
            for (int i = 1; i < NBASIS * NCH; ++i) eq &= (cu[i] == cu[0]);
            ((int*)ws)[WS_FLAG] = eq;
        }
    }
}

// ---------------- Kernel B: main reduction over g -------------------------------------
// Block 256: c = tid&7, tt=(tid>>3)&7, gs=tid>>6 (wave-uniform 4-way g split).
// Grid: NB*(NTARGET/8) = 512 blocks.
__global__ __launch_bounds__(256) void final_layer_kernel(
    const float* __restrict__ x_grid,   // (NB, NGRID, NCH)
    const float* __restrict__ h_grid,   // (NB, NGRID, NBASIS, NCH)
    const float* __restrict__ target_x, // (NB, NTARGET, NCH)
    const float* __restrict__ g_b,      // (1,)
    const float* __restrict__ ws,
    float* __restrict__ out)            // (NB, NTARGET, NCH)
{
    const int tid = threadIdx.x;
    const int c   = tid & 7;
    const int tt  = (tid >> 3) & 7;
    const int gs  = tid >> 6;               // 0..3
    const int b   = blockIdx.x >> 7;
    const int t   = ((blockIdx.x & 127) << 3) + tt;

    const float tx = target_x[(b * NTARGET + t) * NCH + c];
    const float* xg = x_grid + (size_t)(b * NGRID) * NCH + c;
    const int g0 = gs * (NGRID / 4);

    const int uniform = ((const int*)ws)[WS_FLAG];   // wave-uniform branch

    float p;
    if (uniform) {
        // wt is k-independent: out = g_b + sum_g hw[b,g,c] * exp2(coef*d^2)
        const float coefc = ws[WS_COEF + c];
        const float* hwp = ws + WS_HW + (size_t)(b * NGRID) * NCH + c;
        float acc = 0.f;
#pragma unroll 8
        for (int gi = 0; gi < NGRID / 4; ++gi) {
            const int g = g0 + gi;
            const float d = xg[(size_t)g * NCH] - tx;
            acc += hwp[(size_t)g * NCH] * EXP2F(d * d * coefc);
        }
        p = acc;
    } else {
        // general path: per-basis lengthscales
        float coef[NBASIS];
#pragma unroll
        for (int k = 0; k < NBASIS; ++k) coef[k] = ws[WS_COEF + k * NCH + c];
        const float* hg = h_grid + (size_t)(b * NGRID) * NBASIS * NCH + c;
        float acc[NBASIS] = {0.f, 0.f, 0.f, 0.f, 0.f};
#pragma unroll 4
        for (int gi = 0; gi < NGRID / 4; ++gi) {
            const int g = g0 + gi;
            const float d  = xg[(size_t)g * NCH] - tx;
            const float d2 = d * d;
            const float* hp = hg + (size_t)g * NBASIS * NCH;
#pragma unroll
            for (int k = 0; k < NBASIS; ++k)
                acc[k] += hp[k * NCH] * EXP2F(d2 * coef[k]);
        }
        // fold g_w via hw identity not available here; g_w folded in prep only for
        // the uniform path, so reload it from ws? Not stored — use the original
        // trick: g_w lives in coef? No. We must weight by g_w here.
        // (g_w pointer passed below via ws? Simpler: recompute in launch path.)
        p = acc[0]; // placeholder overwritten below
        // NOTE: general path needs g_w; it is appended at ws[41..45] by prep? No —
        // we pass g_w to this kernel directly instead (see signature change).
        (void)p;
        float q = 0.f;
        const float* gw = (const float*)(ws + 48);   // staged by prep? see below
        (void)gw;
        // The general path weights are applied via gw staged at ws[48..52].
        float s = 0.f;
#pragma unroll
        for (int k = 0; k < NBASIS; ++k) s += acc[k] * ws[48 + k];
        p = s;
        (void)q;
    }

    __shared__ float partial[256];
    partial[tid] = p;
    __syncthreads();
    if (gs == 0) {
        float r = p + partial[tid + 64] + partial[tid + 128] + partial[tid + 192]
                + g_b[0];
        out[(b * NTARGET + t) * NCH + c] = r;
    }
}

// Stage g_w into ws[48..52] so the fallback path can use it.
__global__ void stage_gw_kernel(const float* __restrict__ g_w, float* __restrict__ ws) {
    if (threadIdx.x < NBASIS) ws[48 + threadIdx.x] = g_w[threadIdx.x];
}

extern "C" void kernel_launch(void* const* d_in, const int* in_sizes, int n_in,
                              void* d_out, int out_size, void* d_ws, size_t ws_size,
                              hipStream_t stream) {
    const float* x_grid   = (const float*)d_in[0];
    const float* h_grid   = (const float*)d_in[1];
    const float* target_x = (const float*)d_in[2];
    const float* sigma    = (const float*)d_in[3];
    const float* g_w      = (const float*)d_in[4];
    const float* g_b      = (const float*)d_in[5];
    float* out = (float*)d_out;
    float* ws  = (float*)d_ws;

    stage_gw_kernel<<<1, 64, 0, stream>>>(g_w, ws);
    prep_kernel<<<64, 256, 0, stream>>>(h_grid, sigma, g_w, ws);
    final_layer_kernel<<<NB * (NTARGET / 8), 256, 0, stream>>>(
        x_grid, h_grid, target_x, g_b, ws, out);
}

// Round 3
// 69.770 us; speedup vs baseline: 1.1294x; 1.0598x over previous
//
#include <hip/hip_runtime.h>

#define NB 4
#define NGRID 512
#define NTARGET 1024
#define NBASIS 5
#define NCH 8
#define EPS_F 1e-6f
#define LOG2E 1.4426950408889634f

#if defined(__has_builtin)
#if __has_builtin(__builtin_amdgcn_exp2f)
#define EXP2F(x) __builtin_amdgcn_exp2f(x)
#else
#define EXP2F(x) exp2f(x)
#endif
#else
#define EXP2F(x) exp2f(x)
#endif

// Single fused kernel. Grid: NB*(NTARGET/8) = 512 blocks, 256 threads.
// Per block: b = blockIdx>>7, 8 targets, all 8 channels.
//   phase 0: coef[k][c] from sigma (40 exps, redundant per block — trivial)
//   phase 1: stage x_grid[b] (16 KB) and hw[b,g,c] = sum_k g_w[k]*h[b,g,k,c]
//            (16 KB) into LDS — kills the prep-kernel global round-trip.
//   phase 2: uniform-sigma fast path (1 exp/g) out of LDS; general 5-exp
//            fallback if sigma values differ (runtime bit-equality check).
// LDS ~32.3 KB -> 4 blocks/CU. Main-loop LDS reads: 8 distinct banks,
// 8-way same-address broadcast -> conflict-free.
__global__ __launch_bounds__(256) void final_layer_fused(
    const float* __restrict__ x_grid,   // (NB, NGRID, NCH)
    const float* __restrict__ h_grid,   // (NB, NGRID, NBASIS, NCH)
    const float* __restrict__ target_x, // (NB, NTARGET, NCH)
    const float* __restrict__ sigma,    // (NBASIS, NCH)
    const float* __restrict__ g_w,      // (1, NBASIS)
    const float* __restrict__ g_b,      // (1,)
    float* __restrict__ out)            // (NB, NTARGET, NCH)
{
    __shared__ float xs[NGRID * NCH];        // 16 KB; reused as partial buf at end
    __shared__ float hw[NGRID * NCH];        // 16 KB
    __shared__ float coef_s[NBASIS * NCH];
    __shared__ float gw_s[NBASIS];

    const int tid = threadIdx.x;
    const int c   = tid & 7;
    const int tt  = (tid >> 3) & 7;
    const int gs  = tid >> 6;               // 0..3, wave-uniform g-split
    const int b   = blockIdx.x >> 7;
    const int t   = ((blockIdx.x & 127) << 3) + tt;

    // ---- phase 0: coef + gw ----
    if (tid < NBASIS * NCH) {
        float s = __expf(sigma[tid]) + EPS_F;
        coef_s[tid] = -0.5f * LOG2E / (s * s);
    }
    if (tid < NBASIS) gw_s[tid] = g_w[tid];

    // ---- phase 1: stage x, compute hw ----
    const float gw0 = g_w[0], gw1 = g_w[1], gw2 = g_w[2], gw3 = g_w[3], gw4 = g_w[4];
    const float* xbase = x_grid + (size_t)b * NGRID * NCH;
    const float* hbase = h_grid + (size_t)b * NGRID * NBASIS * NCH;
#pragma unroll
    for (int j = 0; j < 16; ++j) {
        const int v = tid + j * 256;                    // (g,c) flat
        xs[v] = xbase[v];
        const float* hp = hbase + (size_t)(v >> 3) * (NBASIS * NCH) + (v & 7);
        hw[v] = gw0 * hp[0] + gw1 * hp[8] + gw2 * hp[16] + gw3 * hp[24] + gw4 * hp[32];
    }
    __syncthreads();

    // uniformity check (bitwise, wave-uniform result)
    int eq = 1;
    {
        const unsigned c0 = __float_as_uint(coef_s[0]);
        for (int i = 1; i < NBASIS * NCH; ++i)
            eq &= (__float_as_uint(coef_s[i]) == c0);
    }

    const float tx = target_x[(b * NTARGET + t) * NCH + c];
    const int g0 = gs * (NGRID / 4);

    float p;
    if (eq) {
        const float coefc = coef_s[c];
        float acc = 0.f;
#pragma unroll 8
        for (int gi = 0; gi < NGRID / 4; ++gi) {
            const int g = g0 + gi;
            const float d = xs[g * 8 + c] - tx;
            acc += hw[g * 8 + c] * EXP2F(d * d * coefc);
        }
        p = acc;
    } else {
        float coef[NBASIS];
#pragma unroll
        for (int k = 0; k < NBASIS; ++k) coef[k] = coef_s[k * NCH + c];
        const float* hg = hbase + c;
        float acc[NBASIS] = {0.f, 0.f, 0.f, 0.f, 0.f};
#pragma unroll 2
        for (int gi = 0; gi < NGRID / 4; ++gi) {
            const int g = g0 + gi;
            const float d  = xs[g * 8 + c] - tx;
            const float d2 = d * d;
            const float* hp = hg + (size_t)g * NBASIS * NCH;
#pragma unroll
            for (int k = 0; k < NBASIS; ++k)
                acc[k] += hp[k * NCH] * EXP2F(d2 * coef[k]);
        }
        float s = 0.f;
#pragma unroll
        for (int k = 0; k < NBASIS; ++k) s += acc[k] * gw_s[k];
        p = s;
    }

    // ---- epilogue: reduce the 4 g-splits (reuse xs as partial buffer) ----
    __syncthreads();
    xs[tid] = p;
    __syncthreads();
    if (gs == 0) {
        float r = p + xs[tid + 64] + xs[tid + 128] + xs[tid + 192] + g_b[0];
        out[(b * NTARGET + t) * NCH + c] = r;
    }
}

extern "C" void kernel_launch(void* const* d_in, const int* in_sizes, int n_in,
                              void* d_out, int out_size, void* d_ws, size_t ws_size,
                              hipStream_t stream) {
    const float* x_grid   = (const float*)d_in[0];
    const float* h_grid   = (const float*)d_in[1];
    const float* target_x = (const float*)d_in[2];
    const float* sigma    = (const float*)d_in[3];
    const float* g_w      = (const float*)d_in[4];
    const float* g_b      = (const float*)d_in[5];
    float* out = (float*)d_out;

    final_layer_fused<<<NB * (NTARGET / 8), 256, 0, stream>>>(
        x_grid, h_grid, target_x, sigma, g_w, g_b, out);
}